// Round 3
// baseline (370.911 us; speedup 1.0000x reference)
//
#include <hip/hip_runtime.h>
#include <math.h>

#define B_ 8
#define T_ 256
#define IDIM_ 128
#define ODIM_ 128
#define HDIM_ 512
#define CDIM_ 128
#define NROWS_ (B_*T_)
#define TEMPER_ 5.0f
#define ENERGY_TH_ 100.0f
#define N_ITER_ 4
#define XPAD_ 384   // [0,127) zeros | [127,255) x | [255,384) zeros

struct WsHeader {
  double loss[N_ITER_];
  unsigned int cnt_y_nz;
  unsigned int cnt_rows_nm;
};

__global__ void k_zero(WsHeader* h) {
  for (int i = 0; i < N_ITER_; ++i) h->loss[i] = 0.0;
  h->cnt_y_nz = 0u;
  h->cnt_rows_nm = 0u;
}

__global__ __launch_bounds__(128) void k_count(const float* __restrict__ y, WsHeader* h) {
  __shared__ int red[128];
  const int row = blockIdx.x, tid = threadIdx.x;
  float v = y[row * ODIM_ + tid];
  red[tid] = (v != 0.0f) ? 1 : 0;
  __syncthreads();
  for (int off = 64; off > 0; off >>= 1) {
    if (tid < off) red[tid] += red[tid + off];
    __syncthreads();
  }
  if (tid == 0) {
    unsigned c = (unsigned)red[0];
    atomicAdd(&h->cnt_y_nz, c);
    if (c > 0) atomicAdd(&h->cnt_rows_nm, 1u);
  }
}

__device__ inline float wsum(float p) {
  #pragma unroll
  for (int off = 32; off; off >>= 1) p += __shfl_xor(p, off, 64);
  return p;
}
__device__ inline float wmaxf(float p) {
  #pragma unroll
  for (int off = 32; off; off >>= 1) p = fmaxf(p, __shfl_xor(p, off, 64));
  return p;
}
__device__ inline void pick(float& v, int& i, float v2, int i2) {
  if (v2 > v || (v2 == v && i2 < i)) { v = v2; i = i2; }
}

// ---- radix-select: top-CDIM_ of 512 keys (8/lane, elem c = lane + 64k).
__device__ inline void radix_topk(const unsigned* key, unsigned* s_hist,
                                  int l, unsigned& t_out, int& rem_out) {
  unsigned prefix = 0u;
  int rem = CDIM_;
  #pragma unroll
  for (int shift = 24; shift >= 0; shift -= 8) {
    unsigned hi_mask = (shift == 24) ? 0u : (0xffffffffu << (shift + 8));
    #pragma unroll
    for (int i = 0; i < 4; ++i) s_hist[4 * l + i] = 0u;
    __threadfence_block();
    #pragma unroll
    for (int k = 0; k < 8; ++k) {
      if ((key[k] & hi_mask) == (prefix & hi_mask))
        atomicAdd(&s_hist[(key[k] >> shift) & 255u], 1u);
    }
    __threadfence_block();
    unsigned h0 = s_hist[4 * l], h1 = s_hist[4 * l + 1];
    unsigned h2 = s_hist[4 * l + 2], h3 = s_hist[4 * l + 3];
    unsigned sum4 = h0 + h1 + h2 + h3;
    unsigned s = sum4;
    #pragma unroll
    for (int off = 1; off < 64; off <<= 1) {
      unsigned o = __shfl(s, min(l + off, 63), 64);
      s += (l + off < 64) ? o : 0u;
    }
    unsigned exclHigh = s - sum4;
    unsigned suf3 = exclHigh;
    unsigned suf2 = suf3 + h3;
    unsigned suf1 = suf2 + h2;
    unsigned suf0 = suf1 + h1;
    unsigned r = (unsigned)rem;
    unsigned enc = 0xffffffffu;
    if (suf0 < r && suf0 + h0 >= r) enc = (suf0 << 8) | (unsigned)(4 * l + 0);
    if (suf1 < r && suf1 + h1 >= r) enc = (suf1 << 8) | (unsigned)(4 * l + 1);
    if (suf2 < r && suf2 + h2 >= r) enc = (suf2 << 8) | (unsigned)(4 * l + 2);
    if (suf3 < r && suf3 + h3 >= r) enc = (suf3 << 8) | (unsigned)(4 * l + 3);
    #pragma unroll
    for (int off = 32; off; off >>= 1) {
      unsigned o = (unsigned)__shfl_xor((int)enc, off, 64);
      enc = (o < enc) ? o : enc;
    }
    rem -= (int)(enc >> 8);
    prefix |= (enc & 255u) << shift;
  }
  t_out = prefix;
  rem_out = rem;
}

__global__ __launch_bounds__(256, 8) void k_main(
    const float* __restrict__ gx, const float* __restrict__ gy,
    const float* __restrict__ enc_w, const float* __restrict__ enc_b,
    const float* __restrict__ dec_w, const float* __restrict__ dec_b,
    WsHeader* __restrict__ hdr)
{
  const int tid = threadIdx.x;
  const int wid = tid >> 6;
  const int l   = tid & 63;
  const int row = blockIdx.x;

  __shared__ __align__(16) float s_xpad[XPAD_];
  __shared__ __align__(16) float s_y[ODIM_];
  __shared__ __align__(16) float s_yatt[ODIM_];
  __shared__ __align__(16) float s_h[HDIM_];
  __shared__ float s_dec[4][ODIM_];
  __shared__ float s_z[ODIM_];
  __shared__ float s_red[ODIM_];
  __shared__ unsigned s_hist[256];
  __shared__ unsigned long long s_pack[CDIM_];
  __shared__ unsigned char s_mprev[HDIM_];
  __shared__ unsigned char s_seqm[ODIM_];
  __shared__ float s_rowlh;
  __shared__ int s_theta;

  const float* gxr = gx + row * IDIM_;
  const float* gyr = gy + row * ODIM_;

  for (int t = tid; t < XPAD_; t += 256)
    s_xpad[t] = (t >= 127 && t < 127 + IDIM_) ? gxr[t - 127] : 0.f;
  if (tid < ODIM_) {
    float v = gyr[tid];
    s_y[tid] = v;
    s_seqm[tid] = (v == 0.0f) ? 1 : 0;
  }
  for (int c = tid; c < HDIM_; c += 256) s_mprev[c] = 0;
  if (tid == 0) s_rowlh = 0.f;
  __syncthreads();

  const float denom_ll = (float)max(hdr->cnt_y_nz, 1u);
  const float denomh   = (float)max(hdr->cnt_rows_nm * (unsigned)HDIM_, 1u);
  const unsigned long long lmask_lt = (l == 0) ? 0ull : ((1ull << l) - 1ull);

  bool sm_row = false;
  if (wid == 0)
    sm_row = (__ballot((s_seqm[l] == 0) || (s_seqm[l + 64] == 0)) == 0ull);

  for (int iter = 0; iter < N_ITER_; ++iter) {
    // ---- stage A: wid0 flushes prev-iter loss; wid1 does sim+argmax
    if (iter > 0 && wid == 0) {
      float row_ll = wsum(s_red[l] + s_red[l + 64]);
      if (l == 0) atomicAdd(&hdr->loss[iter - 1], (double)(row_ll + s_rowlh));
    }
    if (wid == 1) {
      float yl0 = s_y[l], yl1 = s_y[l + 64];
      float normy = sqrtf(wsum(yl0 * yl0 + yl1 * yl1));
      float dot0 = 0, dot1 = 0, dot2 = 0, dot3 = 0;
      float nx0 = 0, nx1 = 0, nx2 = 0, nx3 = 0;
      const int m4 = 4 * l;
      float4 xq0 = *(const float4*)&s_xpad[m4];
      #pragma unroll 4
      for (int jb = 0; jb < 32; ++jb) {
        float4 yq  = *(const float4*)&s_y[4 * jb];
        float4 xq1 = *(const float4*)&s_xpad[m4 + 4 * jb + 4];
        float xa = xq0.x, xb = xq0.y, xc = xq0.z, xd = xq0.w;
        float xe_ = xq1.x, xf = xq1.y, xg = xq1.z;
        dot0 += xa * yq.x; nx0 += xa * xa; dot0 += xb * yq.y; nx0 += xb * xb;
        dot0 += xc * yq.z; nx0 += xc * xc; dot0 += xd * yq.w; nx0 += xd * xd;
        dot1 += xb * yq.x; nx1 += xb * xb; dot1 += xc * yq.y; nx1 += xc * xc;
        dot1 += xd * yq.z; nx1 += xd * xd; dot1 += xe_ * yq.w; nx1 += xe_ * xe_;
        dot2 += xc * yq.x; nx2 += xc * xc; dot2 += xd * yq.y; nx2 += xd * xd;
        dot2 += xe_ * yq.z; nx2 += xe_ * xe_; dot2 += xf * yq.w; nx2 += xf * xf;
        dot3 += xd * yq.x; nx3 += xd * xd; dot3 += xe_ * yq.y; nx3 += xe_ * xe_;
        dot3 += xf * yq.z; nx3 += xf * xf; dot3 += xg * yq.w; nx3 += xg * xg;
        xq0 = xq1;
      }
      float den, sv, bestv; int besti;
      den = normy * sqrtf(nx0); sv = (den == 0.f) ? 0.f : dot0 / den;
      bestv = sv; besti = 4 * l;
      den = normy * sqrtf(nx1); sv = (den == 0.f) ? 0.f : dot1 / den;
      pick(bestv, besti, sv, 4 * l + 1);
      den = normy * sqrtf(nx2); sv = (den == 0.f) ? 0.f : dot2 / den;
      pick(bestv, besti, sv, 4 * l + 2);
      if (4 * l + 3 < 255) {
        den = normy * sqrtf(nx3); sv = (den == 0.f) ? 0.f : dot3 / den;
        pick(bestv, besti, sv, 4 * l + 3);
      }
      #pragma unroll
      for (int off = 32; off; off >>= 1) {
        float ov = __shfl_xor(bestv, off, 64);
        int   oi = __shfl_xor(besti, off, 64);
        pick(bestv, besti, ov, oi);
      }
      if (l == 0) s_theta = besti;
    }
    __syncthreads();
    const int theta = s_theta;

    // ---- stage B: z = y_al * y / T
    if (tid < ODIM_) s_z[tid] = s_xpad[theta + tid] * s_y[tid] / TEMPER_;
    __syncthreads();

    // ---- stage C: softmax -> y_att  (waves 0,1 redundantly reduce)
    if (wid < 2) {
      float z0 = s_z[l], z1 = s_z[l + 64];
      float zmax = wmaxf(fmaxf(z0, z1));
      float e0 = expf(z0 - zmax), e1 = expf(z1 - zmax);
      float esum = wsum(e0 + e1);
      float mye = (wid == 0) ? e0 : e1;
      s_yatt[tid] = s_xpad[theta + tid] * (mye / esum);
    }
    __syncthreads();

    // ---- stage D: h = y_att @ enc_w + enc_b  (c = 2tid, 2tid+1)
    {
      const float* wp = enc_w + 2 * tid;
      float a0 = 0.f, a1 = 0.f;
      #pragma unroll 8
      for (int i4 = 0; i4 < 32; ++i4) {
        float4 yv4 = *(const float4*)&s_yatt[4 * i4];
        float2 w0 = *(const float2*)(wp + (4 * i4 + 0) * HDIM_);
        a0 += yv4.x * w0.x; a1 += yv4.x * w0.y;
        float2 w1 = *(const float2*)(wp + (4 * i4 + 1) * HDIM_);
        a0 += yv4.y * w1.x; a1 += yv4.y * w1.y;
        float2 w2 = *(const float2*)(wp + (4 * i4 + 2) * HDIM_);
        a0 += yv4.z * w2.x; a1 += yv4.z * w2.y;
        float2 w3 = *(const float2*)(wp + (4 * i4 + 3) * HDIM_);
        a0 += yv4.w * w3.x; a1 += yv4.w * w3.y;
      }
      float2 eb = *(const float2*)(enc_b + 2 * tid);
      float2 hv2; hv2.x = a0 + eb.x; hv2.y = a1 + eb.y;
      *(float2*)&s_h[2 * tid] = hv2;
    }
    __syncthreads();

    // ---- stage E: hsr (wid0 only; R2-proven radix/tie semantics)
    if (wid == 0) {
      float hv[8]; unsigned key[8];
      #pragma unroll
      for (int k = 0; k < 8; ++k) {
        hv[k] = s_h[l + 64 * k];
        key[k] = __float_as_uint(hv[k] * hv[k]);
      }
      float rowlh = 0.f;
      if (iter > 0) {
        unsigned t0; int rem0;
        radix_topk(key, s_hist, l, t0, rem0);
        int eqbefore = 0; float lacc = 0.f;
        #pragma unroll
        for (int k = 0; k < 8; ++k) {
          bool eq = (key[k] == t0);
          unsigned long long beq = __ballot(eq);
          int rank = eqbefore + __popcll(beq & lmask_lt);
          bool sel0 = (key[k] > t0) || (eq && rank < rem0);
          eqbefore += __popcll(beq);
          int mp = (int)s_mprev[l + 64 * k];
          if (sel0 && mp > 0 && !sm_row) {
            float d = hv[k] - (1.f - (float)mp);
            lacc += (d * d) / denomh;
          }
        }
        rowlh = wsum(lacc);
        #pragma unroll
        for (int k = 0; k < 8; ++k) {
          if (s_mprev[l + 64 * k] > 0) { hv[k] = 0.f; s_h[l + 64 * k] = 0.f; }
          key[k] = __float_as_uint(hv[k] * hv[k]);
        }
      }
      unsigned t; int rem;
      radix_topk(key, s_hist, l, t, rem);
      int scount = 0, eqbefore = 0;
      #pragma unroll
      for (int k = 0; k < 8; ++k) {
        bool eq = (key[k] == t);
        unsigned long long beq = __ballot(eq);
        int rank = eqbefore + __popcll(beq & lmask_lt);
        bool sel = (key[k] > t) || (eq && rank < rem);
        eqbefore += __popcll(beq);
        unsigned long long mk = __ballot(sel);
        if (sel) {
          int pos = scount + __popcll(mk & lmask_lt);
          s_pack[pos] = (((unsigned long long)__float_as_uint(hv[k])) << 32)
                        | (unsigned)(l + 64 * k);
          s_mprev[l + 64 * k] += 1;
        }
        scount += (int)__popcll(mk);
      }
      if (l == 0) s_rowlh = rowlh;
    }
    __syncthreads();

    // ---- stage F: dec partials (wave w handles 32 selected channels)
    {
      float acc0 = 0.f, acc1 = 0.f;
      #pragma unroll 8
      for (int jj = 0; jj < 32; ++jj) {
        unsigned long long pk = s_pack[32 * wid + jj];
        float hv = __uint_as_float((unsigned)(pk >> 32));
        const float* wr = dec_w + (unsigned)(pk & 0xffffffffull) * (unsigned)ODIM_;
        acc0 += hv * wr[l];
        acc1 += hv * wr[l + 64];
      }
      s_dec[wid][l] = acc0;
      s_dec[wid][l + 64] = acc1;
    }
    __syncthreads();

    // ---- stage G: y_ele, energy loss staging, residual updates
    if (tid < ODIM_) {
      float ye = ((s_dec[0][tid] + s_dec[1][tid]) + s_dec[2][tid]) + s_dec[3][tid]
                 + dec_b[tid];
      float yv = s_y[tid];
      float tshift  = fabsf((float)theta - 127.f);
      float menergy = tshift + 1.f;
      bool  mmask   = (tshift > ENERGY_TH_);
      float d = ye - yv;
      float ll = s_seqm[tid] ? 0.f : d * d;
      ll = ll / denom_ll;
      ll = mmask ? 0.f : ll;
      ll = ll / menergy;
      s_red[tid] = ll;
      int src = tid + 127 - theta;
      float xe = (src >= 0 && src < ODIM_) ? s_yatt[src] : 0.f;
      s_y[tid] = yv - ye;
      s_xpad[127 + tid] -= xe;
    }
    __syncthreads();
  }

  // flush last iter's loss
  if (wid == 0) {
    float row_ll = wsum(s_red[l] + s_red[l + 64]);
    if (l == 0) atomicAdd(&hdr->loss[N_ITER_ - 1], (double)(row_ll + s_rowlh));
  }
}

__global__ void k_finish(const WsHeader* __restrict__ h, float* __restrict__ out) {
  double s = (h->loss[0] + h->loss[1] + h->loss[2] + h->loss[3]) * 0.25;
  out[0] = (float)s;
}

extern "C" void kernel_launch(void* const* d_in, const int* in_sizes, int n_in,
                              void* d_out, int out_size, void* d_ws, size_t ws_size,
                              hipStream_t stream) {
  (void)in_sizes; (void)n_in; (void)out_size; (void)ws_size;
  const float* x     = (const float*)d_in[0];
  const float* y     = (const float*)d_in[1];
  const float* enc_w = (const float*)d_in[2];
  const float* enc_b = (const float*)d_in[3];
  const float* dec_w = (const float*)d_in[4];
  const float* dec_b = (const float*)d_in[5];
  float* out = (float*)d_out;
  WsHeader* hdr = (WsHeader*)d_ws;

  hipLaunchKernelGGL(k_zero,   dim3(1),      dim3(1),   0, stream, hdr);
  hipLaunchKernelGGL(k_count,  dim3(NROWS_), dim3(128), 0, stream, y, hdr);
  hipLaunchKernelGGL(k_main,   dim3(NROWS_), dim3(256), 0, stream,
                     x, y, enc_w, enc_b, dec_w, dec_b, hdr);
  hipLaunchKernelGGL(k_finish, dim3(1),      dim3(1),   0, stream, hdr, out);
}

// Round 4
// 189.880 us; speedup vs baseline: 1.9534x; 1.9534x over previous
//
#include <hip/hip_runtime.h>
#include <math.h>

#define B_ 8
#define T_ 256
#define IDIM_ 128
#define ODIM_ 128
#define HDIM_ 512
#define CDIM_ 128
#define NROWS_ (B_*T_)
#define TEMPER_ 5.0f
#define ENERGY_TH_ 100.0f
#define N_ITER_ 4
#define XPAD_ 384   // [0,127) zeros | [127,255) x | [255,384) zeros
#define RPB_ 4      // rows per block (one wave each)

struct WsHeader {
  double loss[N_ITER_];
  unsigned int cnt_y_nz;
  unsigned int cnt_rows_nm;
};

__global__ void k_zero(WsHeader* h) {
  for (int i = 0; i < N_ITER_; ++i) h->loss[i] = 0.0;
  h->cnt_y_nz = 0u;
  h->cnt_rows_nm = 0u;
}

__global__ __launch_bounds__(128) void k_count(const float* __restrict__ y, WsHeader* h) {
  __shared__ int red[128];
  const int row = blockIdx.x, tid = threadIdx.x;
  float v = y[row * ODIM_ + tid];
  red[tid] = (v != 0.0f) ? 1 : 0;
  __syncthreads();
  for (int off = 64; off > 0; off >>= 1) {
    if (tid < off) red[tid] += red[tid + off];
    __syncthreads();
  }
  if (tid == 0) {
    unsigned c = (unsigned)red[0];
    atomicAdd(&h->cnt_y_nz, c);
    if (c > 0) atomicAdd(&h->cnt_rows_nm, 1u);
  }
}

__device__ inline float wsum(float p) {
  #pragma unroll
  for (int off = 32; off; off >>= 1) p += __shfl_xor(p, off, 64);
  return p;
}
__device__ inline float wmaxf(float p) {
  #pragma unroll
  for (int off = 32; off; off >>= 1) p = fmaxf(p, __shfl_xor(p, off, 64));
  return p;
}
__device__ inline void pick(float& v, int& i, float v2, int i2) {
  if (v2 > v || (v2 == v && i2 < i)) { v = v2; i = i2; }
}

// ---- radix-select: top-CDIM_ of 512 keys (8/lane, elem c = lane + 64k).
__device__ inline void radix_topk(const unsigned* key, unsigned* s_hist,
                                  int l, unsigned& t_out, int& rem_out) {
  unsigned prefix = 0u;
  int rem = CDIM_;
  #pragma unroll
  for (int shift = 24; shift >= 0; shift -= 8) {
    unsigned hi_mask = (shift == 24) ? 0u : (0xffffffffu << (shift + 8));
    #pragma unroll
    for (int i = 0; i < 4; ++i) s_hist[4 * l + i] = 0u;
    __threadfence_block();
    #pragma unroll
    for (int k = 0; k < 8; ++k) {
      if ((key[k] & hi_mask) == (prefix & hi_mask))
        atomicAdd(&s_hist[(key[k] >> shift) & 255u], 1u);
    }
    __threadfence_block();
    unsigned h0 = s_hist[4 * l], h1 = s_hist[4 * l + 1];
    unsigned h2 = s_hist[4 * l + 2], h3 = s_hist[4 * l + 3];
    unsigned sum4 = h0 + h1 + h2 + h3;
    unsigned s = sum4;
    #pragma unroll
    for (int off = 1; off < 64; off <<= 1) {
      unsigned o = __shfl(s, min(l + off, 63), 64);
      s += (l + off < 64) ? o : 0u;
    }
    unsigned exclHigh = s - sum4;
    unsigned suf3 = exclHigh;
    unsigned suf2 = suf3 + h3;
    unsigned suf1 = suf2 + h2;
    unsigned suf0 = suf1 + h1;
    unsigned r = (unsigned)rem;
    unsigned enc = 0xffffffffu;
    if (suf0 < r && suf0 + h0 >= r) enc = (suf0 << 8) | (unsigned)(4 * l + 0);
    if (suf1 < r && suf1 + h1 >= r) enc = (suf1 << 8) | (unsigned)(4 * l + 1);
    if (suf2 < r && suf2 + h2 >= r) enc = (suf2 << 8) | (unsigned)(4 * l + 2);
    if (suf3 < r && suf3 + h3 >= r) enc = (suf3 << 8) | (unsigned)(4 * l + 3);
    #pragma unroll
    for (int off = 32; off; off >>= 1) {
      unsigned o = (unsigned)__shfl_xor((int)enc, off, 64);
      enc = (o < enc) ? o : enc;
    }
    rem -= (int)(enc >> 8);
    prefix |= (enc & 255u) << shift;
  }
  t_out = prefix;
  rem_out = rem;
}

__global__ __launch_bounds__(256, 2) void k_main(
    const float* __restrict__ gx, const float* __restrict__ gy,
    const float* __restrict__ enc_w, const float* __restrict__ enc_b,
    const float* __restrict__ dec_w, const float* __restrict__ dec_b,
    WsHeader* __restrict__ hdr)
{
  const int tid = threadIdx.x;
  const int wid = tid >> 6;
  const int l   = tid & 63;
  const int row = blockIdx.x * RPB_ + wid;

  __shared__ __align__(16) float s_xpad[RPB_][XPAD_];
  __shared__ __align__(16) float s_y[RPB_][ODIM_];
  __shared__ __align__(16) float s_yatt[RPB_][ODIM_];
  __shared__ __align__(16) float s_h[RPB_][HDIM_];
  __shared__ unsigned s_hist[RPB_][256];
  __shared__ unsigned long long s_pack[RPB_][CDIM_];

  float* m_xpad = s_xpad[wid];
  float* m_y    = s_y[wid];
  unsigned* m_hist = s_hist[wid];
  unsigned long long* m_pack = s_pack[wid];

  const unsigned long long lmask_lt = (l == 0) ? 0ull : ((1ull << l) - 1ull);
  const float* gxr = gx + row * IDIM_;
  const float* gyr = gy + row * ODIM_;

  #pragma unroll
  for (int t = l; t < XPAD_; t += 64)
    m_xpad[t] = (t >= 127 && t < 127 + IDIM_) ? gxr[t - 127] : 0.f;

  float y0 = gyr[l], y1 = gyr[l + 64];
  m_y[l] = y0; m_y[l + 64] = y1;
  const bool sq0 = (y0 == 0.f), sq1 = (y1 == 0.f);
  const bool sm_row = (__ballot((!sq0) || (!sq1)) == 0ull);

  const float denom_ll = (float)max(hdr->cnt_y_nz, 1u);
  const float denomh   = (float)max(hdr->cnt_rows_nm * (unsigned)HDIM_, 1u);

  int mprev[8];
  #pragma unroll
  for (int k = 0; k < 8; ++k) mprev[k] = 0;

  __syncthreads();

  for (int iter = 0; iter < N_ITER_; ++iter) {
    // ================= stage A (wave-local): sim + argmax + softmax =======
    float normy = sqrtf(wsum(y0 * y0 + y1 * y1));
    float dot0 = 0, dot1 = 0, dot2 = 0, dot3 = 0;
    float nx0 = 0, nx1 = 0, nx2 = 0, nx3 = 0;
    {
      const int m4 = 4 * l;
      float4 xq0 = *(const float4*)&m_xpad[m4];
      #pragma unroll 4
      for (int jb = 0; jb < 32; ++jb) {
        float4 yq  = *(const float4*)&m_y[4 * jb];
        float4 xq1 = *(const float4*)&m_xpad[m4 + 4 * jb + 4];
        float xa = xq0.x, xb = xq0.y, xc = xq0.z, xd = xq0.w;
        float xe_ = xq1.x, xf = xq1.y, xg = xq1.z;
        dot0 += xa * yq.x; nx0 += xa * xa; dot0 += xb * yq.y; nx0 += xb * xb;
        dot0 += xc * yq.z; nx0 += xc * xc; dot0 += xd * yq.w; nx0 += xd * xd;
        dot1 += xb * yq.x; nx1 += xb * xb; dot1 += xc * yq.y; nx1 += xc * xc;
        dot1 += xd * yq.z; nx1 += xd * xd; dot1 += xe_ * yq.w; nx1 += xe_ * xe_;
        dot2 += xc * yq.x; nx2 += xc * xc; dot2 += xd * yq.y; nx2 += xd * xd;
        dot2 += xe_ * yq.z; nx2 += xe_ * xe_; dot2 += xf * yq.w; nx2 += xf * xf;
        dot3 += xd * yq.x; nx3 += xd * xd; dot3 += xe_ * yq.y; nx3 += xe_ * xe_;
        dot3 += xf * yq.z; nx3 += xf * xf; dot3 += xg * yq.w; nx3 += xg * xg;
        xq0 = xq1;
      }
    }
    float den, sv, bestv; int besti;
    den = normy * sqrtf(nx0); sv = (den == 0.f) ? 0.f : dot0 / den;
    bestv = sv; besti = 4 * l;
    den = normy * sqrtf(nx1); sv = (den == 0.f) ? 0.f : dot1 / den;
    pick(bestv, besti, sv, 4 * l + 1);
    den = normy * sqrtf(nx2); sv = (den == 0.f) ? 0.f : dot2 / den;
    pick(bestv, besti, sv, 4 * l + 2);
    if (4 * l + 3 < 255) {
      den = normy * sqrtf(nx3); sv = (den == 0.f) ? 0.f : dot3 / den;
      pick(bestv, besti, sv, 4 * l + 3);
    }
    #pragma unroll
    for (int off = 32; off; off >>= 1) {
      float ov = __shfl_xor(bestv, off, 64);
      int   oi = __shfl_xor(besti, off, 64);
      pick(bestv, besti, ov, oi);
    }
    const int theta = besti;

    // softmax(y_al * y_res / T) -> y_att
    float yal0 = m_xpad[theta + l];
    float yal1 = m_xpad[theta + l + 64];
    float z0 = yal0 * y0 / TEMPER_;
    float z1 = yal1 * y1 / TEMPER_;
    float zmax = wmaxf(fmaxf(z0, z1));
    float e0 = expf(z0 - zmax), e1 = expf(z1 - zmax);
    float esum = wsum(e0 + e1);
    float ya0 = yal0 * (e0 / esum);
    float ya1 = yal1 * (e1 / esum);
    s_yatt[wid][l] = ya0;
    s_yatt[wid][l + 64] = ya1;
    __syncthreads();

    // ========== stage B (cooperative): h[r] = y_att[r] @ enc_w + enc_b ====
    // thread -> cols (2tid, 2tid+1), all 4 rows; 16-deep load chunks for MLP
    {
      const float* wp = enc_w + 2 * tid;
      float a00 = 0, a01 = 0, a10 = 0, a11 = 0;
      float a20 = 0, a21 = 0, a30 = 0, a31 = 0;
      #pragma unroll 1
      for (int ch = 0; ch < 8; ++ch) {
        float2 w[16];
        #pragma unroll
        for (int k = 0; k < 16; ++k)
          w[k] = *(const float2*)(wp + (16 * ch + k) * HDIM_);
        float4 ya[RPB_][4];
        #pragma unroll
        for (int r = 0; r < RPB_; ++r) {
          #pragma unroll
          for (int q = 0; q < 4; ++q)
            ya[r][q] = *(const float4*)&s_yatt[r][16 * ch + 4 * q];
        }
        #pragma unroll
        for (int k = 0; k < 16; ++k) {
          const float2 wv = w[k];
          const float v0 = ((const float*)&ya[0][0])[k];
          const float v1 = ((const float*)&ya[1][0])[k];
          const float v2 = ((const float*)&ya[2][0])[k];
          const float v3 = ((const float*)&ya[3][0])[k];
          a00 += v0 * wv.x; a01 += v0 * wv.y;
          a10 += v1 * wv.x; a11 += v1 * wv.y;
          a20 += v2 * wv.x; a21 += v2 * wv.y;
          a30 += v3 * wv.x; a31 += v3 * wv.y;
        }
      }
      float2 eb = *(const float2*)(enc_b + 2 * tid);
      float2 o0 = {a00 + eb.x, a01 + eb.y};
      float2 o1 = {a10 + eb.x, a11 + eb.y};
      float2 o2 = {a20 + eb.x, a21 + eb.y};
      float2 o3 = {a30 + eb.x, a31 + eb.y};
      *(float2*)&s_h[0][2 * tid] = o0;
      *(float2*)&s_h[1][2 * tid] = o1;
      *(float2*)&s_h[2][2 * tid] = o2;
      *(float2*)&s_h[3][2 * tid] = o3;
    }
    __syncthreads();

    // ============== stage C (wave-local): hsr + dec + loss + residuals ====
    float hv[8]; unsigned key[8];
    #pragma unroll
    for (int k = 0; k < 8; ++k) {
      hv[k] = s_h[wid][l + 64 * k];
      key[k] = __float_as_uint(hv[k] * hv[k]);
    }
    float row_lh = 0.f;
    if (iter > 0) {
      unsigned t0; int rem0;
      radix_topk(key, m_hist, l, t0, rem0);
      int eqbefore = 0; float lacc = 0.f;
      #pragma unroll
      for (int k = 0; k < 8; ++k) {
        bool eq = (key[k] == t0);
        unsigned long long beq = __ballot(eq);
        int rank = eqbefore + __popcll(beq & lmask_lt);
        bool sel0 = (key[k] > t0) || (eq && rank < rem0);
        eqbefore += __popcll(beq);
        if (sel0 && mprev[k] > 0 && !sm_row) {
          float d = hv[k] - (1.f - (float)mprev[k]);
          lacc += (d * d) / denomh;
        }
      }
      row_lh = wsum(lacc);
      #pragma unroll
      for (int k = 0; k < 8; ++k) {
        if (mprev[k] > 0) hv[k] = 0.f;
        key[k] = __float_as_uint(hv[k] * hv[k]);
      }
    }
    {
      unsigned t; int rem;
      radix_topk(key, m_hist, l, t, rem);
      int scount = 0, eqbefore = 0;
      #pragma unroll
      for (int k = 0; k < 8; ++k) {
        bool eq = (key[k] == t);
        unsigned long long beq = __ballot(eq);
        int rank = eqbefore + __popcll(beq & lmask_lt);
        bool sel = (key[k] > t) || (eq && rank < rem);
        eqbefore += __popcll(beq);
        unsigned long long mk = __ballot(sel);
        if (sel) {
          int pos = scount + __popcll(mk & lmask_lt);
          m_pack[pos] = (((unsigned long long)__float_as_uint(hv[k])) << 32)
                        | (unsigned)(l + 64 * k);
          mprev[k] += 1;
        }
        scount += (int)__popcll(mk);
      }
    }

    // dec gather: ascending selected channels, 16-deep load chunks for MLP
    float acc0 = 0.f, acc1 = 0.f;
    #pragma unroll 1
    for (int ch = 0; ch < 8; ++ch) {
      float hj[16], w0[16], w1[16];
      #pragma unroll
      for (int j = 0; j < 16; ++j) {
        unsigned long long pk = m_pack[16 * ch + j];
        hj[j] = __uint_as_float((unsigned)(pk >> 32));
        const float* p = dec_w + (unsigned)(pk & 0xffffffffull) * (unsigned)ODIM_;
        w0[j] = p[l];
        w1[j] = p[l + 64];
      }
      #pragma unroll
      for (int j = 0; j < 16; ++j) {
        acc0 += hj[j] * w0[j];
        acc1 += hj[j] * w1[j];
      }
    }
    float ye0 = acc0 + dec_b[l];
    float ye1 = acc1 + dec_b[l + 64];

    // energy loss
    float tshift  = fabsf((float)theta - 127.f);
    float menergy = tshift + 1.f;
    bool  mmask   = (tshift > ENERGY_TH_);
    float d0 = ye0 - y0, d1 = ye1 - y1;
    float ll0 = sq0 ? 0.f : d0 * d0; ll0 /= denom_ll; ll0 = mmask ? 0.f : ll0; ll0 /= menergy;
    float ll1 = sq1 ? 0.f : d1 * d1; ll1 /= denom_ll; ll1 = mmask ? 0.f : ll1; ll1 /= menergy;
    float row_ll = wsum(ll0 + ll1);
    if (l == 0) atomicAdd(&hdr->loss[iter], (double)(row_ll + row_lh));

    // residual updates (own row only)
    int src0 = l + 127 - theta;
    int src1 = l + 64 + 127 - theta;
    float xe0 = (src0 >= 0 && src0 < ODIM_) ? s_yatt[wid][src0] : 0.f;
    float xe1 = (src1 >= 0 && src1 < ODIM_) ? s_yatt[wid][src1] : 0.f;
    y0 -= ye0; y1 -= ye1;
    m_y[l] = y0; m_y[l + 64] = y1;
    m_xpad[127 + l] -= xe0;
    m_xpad[127 + 64 + l] -= xe1;
    // next stage-A reads only own-row LDS; barrier at top of stage B orders
    // the cross-wave s_yatt/s_h reuse.
  }
}

__global__ void k_finish(const WsHeader* __restrict__ h, float* __restrict__ out) {
  double s = (h->loss[0] + h->loss[1] + h->loss[2] + h->loss[3]) * 0.25;
  out[0] = (float)s;
}

extern "C" void kernel_launch(void* const* d_in, const int* in_sizes, int n_in,
                              void* d_out, int out_size, void* d_ws, size_t ws_size,
                              hipStream_t stream) {
  (void)in_sizes; (void)n_in; (void)out_size; (void)ws_size;
  const float* x     = (const float*)d_in[0];
  const float* y     = (const float*)d_in[1];
  const float* enc_w = (const float*)d_in[2];
  const float* enc_b = (const float*)d_in[3];
  const float* dec_w = (const float*)d_in[4];
  const float* dec_b = (const float*)d_in[5];
  float* out = (float*)d_out;
  WsHeader* hdr = (WsHeader*)d_ws;

  hipLaunchKernelGGL(k_zero,   dim3(1),            dim3(1),   0, stream, hdr);
  hipLaunchKernelGGL(k_count,  dim3(NROWS_),       dim3(128), 0, stream, y, hdr);
  hipLaunchKernelGGL(k_main,   dim3(NROWS_/RPB_),  dim3(256), 0, stream,
                     x, y, enc_w, enc_b, dec_w, dec_b, hdr);
  hipLaunchKernelGGL(k_finish, dim3(1),            dim3(1),   0, stream, hdr, out);
}

// Round 5
// 168.028 us; speedup vs baseline: 2.2074x; 1.1300x over previous
//
#include <hip/hip_runtime.h>
#include <math.h>

#define B_ 8
#define T_ 256
#define IDIM_ 128
#define ODIM_ 128
#define HDIM_ 512
#define CDIM_ 128
#define NROWS_ (B_*T_)
#define TEMPER_ 5.0f
#define ENERGY_TH_ 100.0f
#define N_ITER_ 4
#define XPAD_ 384   // [0,127) zeros | [127,255) x | [255,384) zeros
#define RPB_ 4      // rows per block, 2 waves each -> 512 threads

struct WsHeader {
  double loss[N_ITER_];
  unsigned int cnt_y_nz;
  unsigned int cnt_rows_nm;
};

// 8 blocks x 256 threads; one row per thread
__global__ __launch_bounds__(256) void k_count(const float* __restrict__ y,
                                               WsHeader* __restrict__ h) {
  __shared__ unsigned redn[256];
  __shared__ unsigned redr[256];
  const int tid = threadIdx.x;
  const int row = blockIdx.x * 256 + tid;
  const float4* yr = (const float4*)(y + row * ODIM_);
  unsigned c = 0;
  #pragma unroll 8
  for (int i = 0; i < 32; ++i) {
    float4 v = yr[i];
    c += (v.x != 0.f) + (v.y != 0.f) + (v.z != 0.f) + (v.w != 0.f);
  }
  redn[tid] = c;
  redr[tid] = (c > 0u) ? 1u : 0u;
  __syncthreads();
  for (int off = 128; off > 0; off >>= 1) {
    if (tid < off) { redn[tid] += redn[tid + off]; redr[tid] += redr[tid + off]; }
    __syncthreads();
  }
  if (tid == 0) {
    atomicAdd(&h->cnt_y_nz, redn[0]);
    atomicAdd(&h->cnt_rows_nm, redr[0]);
  }
}

__device__ inline float wsum(float p) {
  #pragma unroll
  for (int off = 32; off; off >>= 1) p += __shfl_xor(p, off, 64);
  return p;
}
__device__ inline float wmaxf(float p) {
  #pragma unroll
  for (int off = 32; off; off >>= 1) p = fmaxf(p, __shfl_xor(p, off, 64));
  return p;
}
__device__ inline void pick(float& v, int& i, float v2, int i2) {
  if (v2 > v || (v2 == v && i2 < i)) { v = v2; i = i2; }
}

// ---- radix-select: top-CDIM_ of 512 keys (8/lane, elem c = lane + 64k).
__device__ inline void radix_topk(const unsigned* key, unsigned* s_hist,
                                  int l, unsigned& t_out, int& rem_out) {
  unsigned prefix = 0u;
  int rem = CDIM_;
  #pragma unroll
  for (int shift = 24; shift >= 0; shift -= 8) {
    unsigned hi_mask = (shift == 24) ? 0u : (0xffffffffu << (shift + 8));
    #pragma unroll
    for (int i = 0; i < 4; ++i) s_hist[4 * l + i] = 0u;
    __threadfence_block();
    #pragma unroll
    for (int k = 0; k < 8; ++k) {
      if ((key[k] & hi_mask) == (prefix & hi_mask))
        atomicAdd(&s_hist[(key[k] >> shift) & 255u], 1u);
    }
    __threadfence_block();
    unsigned h0 = s_hist[4 * l], h1 = s_hist[4 * l + 1];
    unsigned h2 = s_hist[4 * l + 2], h3 = s_hist[4 * l + 3];
    unsigned sum4 = h0 + h1 + h2 + h3;
    unsigned s = sum4;
    #pragma unroll
    for (int off = 1; off < 64; off <<= 1) {
      unsigned o = __shfl(s, min(l + off, 63), 64);
      s += (l + off < 64) ? o : 0u;
    }
    unsigned exclHigh = s - sum4;
    unsigned suf3 = exclHigh;
    unsigned suf2 = suf3 + h3;
    unsigned suf1 = suf2 + h2;
    unsigned suf0 = suf1 + h1;
    unsigned r = (unsigned)rem;
    unsigned enc = 0xffffffffu;
    if (suf0 < r && suf0 + h0 >= r) enc = (suf0 << 8) | (unsigned)(4 * l + 0);
    if (suf1 < r && suf1 + h1 >= r) enc = (suf1 << 8) | (unsigned)(4 * l + 1);
    if (suf2 < r && suf2 + h2 >= r) enc = (suf2 << 8) | (unsigned)(4 * l + 2);
    if (suf3 < r && suf3 + h3 >= r) enc = (suf3 << 8) | (unsigned)(4 * l + 3);
    #pragma unroll
    for (int off = 32; off; off >>= 1) {
      unsigned o = (unsigned)__shfl_xor((int)enc, off, 64);
      enc = (o < enc) ? o : enc;
    }
    rem -= (int)(enc >> 8);
    prefix |= (enc & 255u) << shift;
  }
  t_out = prefix;
  rem_out = rem;
}

__global__ __launch_bounds__(512, 4) void k_main(
    const float* __restrict__ gx, const float* __restrict__ gy,
    const float* __restrict__ enc_w, const float* __restrict__ enc_b,
    const float* __restrict__ dec_w, const float* __restrict__ dec_b,
    WsHeader* __restrict__ hdr)
{
  const int tid = threadIdx.x;
  const int wid = tid >> 6;     // 0..7
  const int l   = tid & 63;
  const int r   = wid >> 1;     // row-in-block 0..3
  const int sub = wid & 1;      // wave within pair
  const int row = blockIdx.x * RPB_ + r;

  __shared__ __align__(16) float s_xpad[RPB_][XPAD_];
  __shared__ __align__(16) float s_y[RPB_][ODIM_];
  __shared__ __align__(16) float s_yatt[RPB_][ODIM_];
  __shared__ __align__(16) float s_h[RPB_][HDIM_];
  __shared__ __align__(16) float s_dot[RPB_][2][256];
  __shared__ __align__(16) float s_nx[RPB_][2][256];
  __shared__ float s_dpart[RPB_][2][ODIM_];
  __shared__ float s_scal[RPB_][2];
  __shared__ unsigned s_hist[RPB_][256];
  __shared__ unsigned long long s_pack[RPB_][CDIM_];

  float* m_xpad = s_xpad[r];
  float* m_y    = s_y[r];
  unsigned* m_hist = s_hist[r];
  unsigned long long* m_pack = s_pack[r];

  const unsigned long long lmask_lt = (l == 0) ? 0ull : ((1ull << l) - 1ull);
  const float* gxr = gx + row * IDIM_;
  const float* gyr = gy + row * ODIM_;

  // init: pair splits xpad; sub0 owns y registers + y LDS
  for (int t = l + 64 * sub; t < XPAD_; t += 128)
    m_xpad[t] = (t >= 127 && t < 127 + IDIM_) ? gxr[t - 127] : 0.f;

  float y0 = 0.f, y1 = 0.f;
  bool sq0 = false, sq1 = false, sm_row = false;
  if (sub == 0) {
    y0 = gyr[l]; y1 = gyr[l + 64];
    m_y[l] = y0; m_y[l + 64] = y1;
    sq0 = (y0 == 0.f); sq1 = (y1 == 0.f);
    sm_row = (__ballot((!sq0) || (!sq1)) == 0ull);
  }
  const float denom_ll = (float)max(hdr->cnt_y_nz, 1u);
  const float denomh   = (float)max(hdr->cnt_rows_nm * (unsigned)HDIM_, 1u);

  int mprev[8];
  #pragma unroll
  for (int k = 0; k < 8; ++k) mprev[k] = 0;

  int theta = 0;
  float row_lh = 0.f;

  __syncthreads();

  for (int iter = 0; iter < N_ITER_; ++iter) {
    // ========== P0: sim partials (each wave: half the j-range) ==========
    {
      const int jbase = 64 * sub;
      float yv = m_y[jbase + l];
      float pn = wsum(yv * yv);
      if (l == 0) s_scal[r][sub] = pn;

      float dot0 = 0, dot1 = 0, dot2 = 0, dot3 = 0;
      float nx0 = 0, nx1 = 0, nx2 = 0, nx3 = 0;
      const int m4 = 4 * l;
      float4 xq0 = *(const float4*)&m_xpad[m4 + jbase];
      #pragma unroll 4
      for (int jb = 0; jb < 16; ++jb) {
        float4 yq  = *(const float4*)&m_y[jbase + 4 * jb];
        float4 xq1 = *(const float4*)&m_xpad[m4 + jbase + 4 * jb + 4];
        float xa = xq0.x, xb = xq0.y, xc = xq0.z, xd = xq0.w;
        float xe_ = xq1.x, xf = xq1.y, xg = xq1.z;
        dot0 += xa * yq.x; nx0 += xa * xa; dot0 += xb * yq.y; nx0 += xb * xb;
        dot0 += xc * yq.z; nx0 += xc * xc; dot0 += xd * yq.w; nx0 += xd * xd;
        dot1 += xb * yq.x; nx1 += xb * xb; dot1 += xc * yq.y; nx1 += xc * xc;
        dot1 += xd * yq.z; nx1 += xd * xd; dot1 += xe_ * yq.w; nx1 += xe_ * xe_;
        dot2 += xc * yq.x; nx2 += xc * xc; dot2 += xd * yq.y; nx2 += xd * xd;
        dot2 += xe_ * yq.z; nx2 += xe_ * xe_; dot2 += xf * yq.w; nx2 += xf * xf;
        dot3 += xd * yq.x; nx3 += xd * xd; dot3 += xe_ * yq.y; nx3 += xe_ * xe_;
        dot3 += xf * yq.z; nx3 += xf * xf; dot3 += xg * yq.w; nx3 += xg * xg;
        xq0 = xq1;
      }
      float4 dq = {dot0, dot1, dot2, dot3};
      float4 nq = {nx0, nx1, nx2, nx3};
      *(float4*)&s_dot[r][sub][m4] = dq;
      *(float4*)&s_nx[r][sub][m4]  = nq;
    }
    __syncthreads();

    // ========== P1 (sub0): combine + argmax + softmax ==========
    if (sub == 0) {
      const float normy = sqrtf(s_scal[r][0] + s_scal[r][1]);
      float4 dA = *(const float4*)&s_dot[r][0][4 * l];
      float4 dB = *(const float4*)&s_dot[r][1][4 * l];
      float4 nA = *(const float4*)&s_nx[r][0][4 * l];
      float4 nB = *(const float4*)&s_nx[r][1][4 * l];
      float dot0 = dA.x + dB.x, dot1 = dA.y + dB.y;
      float dot2 = dA.z + dB.z, dot3 = dA.w + dB.w;
      float nx0 = nA.x + nB.x, nx1 = nA.y + nB.y;
      float nx2 = nA.z + nB.z, nx3 = nA.w + nB.w;
      float den, sv, bestv; int besti;
      den = normy * sqrtf(nx0); sv = (den == 0.f) ? 0.f : dot0 / den;
      bestv = sv; besti = 4 * l;
      den = normy * sqrtf(nx1); sv = (den == 0.f) ? 0.f : dot1 / den;
      pick(bestv, besti, sv, 4 * l + 1);
      den = normy * sqrtf(nx2); sv = (den == 0.f) ? 0.f : dot2 / den;
      pick(bestv, besti, sv, 4 * l + 2);
      if (4 * l + 3 < 255) {
        den = normy * sqrtf(nx3); sv = (den == 0.f) ? 0.f : dot3 / den;
        pick(bestv, besti, sv, 4 * l + 3);
      }
      #pragma unroll
      for (int off = 32; off; off >>= 1) {
        float ov = __shfl_xor(bestv, off, 64);
        int   oi = __shfl_xor(besti, off, 64);
        pick(bestv, besti, ov, oi);
      }
      theta = besti;

      float yal0 = m_xpad[theta + l];
      float yal1 = m_xpad[theta + l + 64];
      float z0 = yal0 * y0 / TEMPER_;
      float z1 = yal1 * y1 / TEMPER_;
      float zmax = wmaxf(fmaxf(z0, z1));
      float e0 = expf(z0 - zmax), e1 = expf(z1 - zmax);
      float esum = wsum(e0 + e1);
      s_yatt[r][l]      = yal0 * (e0 / esum);
      s_yatt[r][l + 64] = yal1 * (e1 / esum);
    }
    __syncthreads();

    // ========== P2 (all 512 threads): h[r'] = y_att[r'] @ enc_w + enc_b ====
    {
      const int c = tid;                    // one column per thread
      const float* wp = enc_w + c;
      float a0 = 0.f, a1 = 0.f, a2 = 0.f, a3 = 0.f;
      #pragma unroll 1
      for (int ch = 0; ch < 8; ++ch) {
        float w[16];
        #pragma unroll
        for (int k = 0; k < 16; ++k) w[k] = wp[(16 * ch + k) * HDIM_];
        #pragma unroll
        for (int q = 0; q < 4; ++q) {
          float4 ya0q = *(const float4*)&s_yatt[0][16 * ch + 4 * q];
          float4 ya1q = *(const float4*)&s_yatt[1][16 * ch + 4 * q];
          float4 ya2q = *(const float4*)&s_yatt[2][16 * ch + 4 * q];
          float4 ya3q = *(const float4*)&s_yatt[3][16 * ch + 4 * q];
          #pragma unroll
          for (int u = 0; u < 4; ++u) {
            float wv = w[4 * q + u];
            a0 += ((const float*)&ya0q)[u] * wv;
            a1 += ((const float*)&ya1q)[u] * wv;
            a2 += ((const float*)&ya2q)[u] * wv;
            a3 += ((const float*)&ya3q)[u] * wv;
          }
        }
      }
      float eb = enc_b[c];
      s_h[0][c] = a0 + eb;
      s_h[1][c] = a1 + eb;
      s_h[2][c] = a2 + eb;
      s_h[3][c] = a3 + eb;
    }
    __syncthreads();

    // ========== P3 (sub0): hsr radix + pack ==========
    if (sub == 0) {
      float hv[8]; unsigned key[8];
      #pragma unroll
      for (int k = 0; k < 8; ++k) {
        hv[k] = s_h[r][l + 64 * k];
        key[k] = __float_as_uint(hv[k] * hv[k]);
      }
      row_lh = 0.f;
      if (iter > 0) {
        unsigned t0; int rem0;
        radix_topk(key, m_hist, l, t0, rem0);
        int eqbefore = 0; float lacc = 0.f;
        #pragma unroll
        for (int k = 0; k < 8; ++k) {
          bool eq = (key[k] == t0);
          unsigned long long beq = __ballot(eq);
          int rank = eqbefore + __popcll(beq & lmask_lt);
          bool sel0 = (key[k] > t0) || (eq && rank < rem0);
          eqbefore += __popcll(beq);
          if (sel0 && mprev[k] > 0 && !sm_row) {
            float d = hv[k] - (1.f - (float)mprev[k]);
            lacc += (d * d) / denomh;
          }
        }
        row_lh = wsum(lacc);
        #pragma unroll
        for (int k = 0; k < 8; ++k) {
          if (mprev[k] > 0) hv[k] = 0.f;
          key[k] = __float_as_uint(hv[k] * hv[k]);
        }
      }
      unsigned t; int rem;
      radix_topk(key, m_hist, l, t, rem);
      int scount = 0, eqbefore = 0;
      #pragma unroll
      for (int k = 0; k < 8; ++k) {
        bool eq = (key[k] == t);
        unsigned long long beq = __ballot(eq);
        int rank = eqbefore + __popcll(beq & lmask_lt);
        bool sel = (key[k] > t) || (eq && rank < rem);
        eqbefore += __popcll(beq);
        unsigned long long mk = __ballot(sel);
        if (sel) {
          int pos = scount + __popcll(mk & lmask_lt);
          m_pack[pos] = (((unsigned long long)__float_as_uint(hv[k])) << 32)
                        | (unsigned)(l + 64 * k);
          mprev[k] += 1;
        }
        scount += (int)__popcll(mk);
      }
    }
    __syncthreads();

    // ========== P4: dec partials (each wave: 64 selected channels) ==========
    {
      float acc0 = 0.f, acc1 = 0.f;
      #pragma unroll 1
      for (int ch = 0; ch < 4; ++ch) {
        float hj[16], w0[16], w1[16];
        #pragma unroll
        for (int j = 0; j < 16; ++j) {
          unsigned long long pk = m_pack[64 * sub + 16 * ch + j];
          hj[j] = __uint_as_float((unsigned)(pk >> 32));
          const float* p = dec_w + (unsigned)(pk & 0xffffffffull) * (unsigned)ODIM_;
          w0[j] = p[l];
          w1[j] = p[l + 64];
        }
        #pragma unroll
        for (int j = 0; j < 16; ++j) {
          acc0 += hj[j] * w0[j];
          acc1 += hj[j] * w1[j];
        }
      }
      s_dpart[r][sub][l]      = acc0;
      s_dpart[r][sub][l + 64] = acc1;
    }
    __syncthreads();

    // ========== P5 (sub0): y_ele, loss, residuals ==========
    if (sub == 0) {
      float ye0 = (s_dpart[r][0][l]      + s_dpart[r][1][l])      + dec_b[l];
      float ye1 = (s_dpart[r][0][l + 64] + s_dpart[r][1][l + 64]) + dec_b[l + 64];

      float tshift  = fabsf((float)theta - 127.f);
      float menergy = tshift + 1.f;
      bool  mmask   = (tshift > ENERGY_TH_);
      float d0 = ye0 - y0, d1 = ye1 - y1;
      float ll0 = sq0 ? 0.f : d0 * d0; ll0 /= denom_ll; ll0 = mmask ? 0.f : ll0; ll0 /= menergy;
      float ll1 = sq1 ? 0.f : d1 * d1; ll1 /= denom_ll; ll1 = mmask ? 0.f : ll1; ll1 /= menergy;
      float row_ll = wsum(ll0 + ll1);
      if (l == 0) atomicAdd(&hdr->loss[iter], (double)(row_ll + row_lh));

      int src0 = l + 127 - theta;
      int src1 = l + 64 + 127 - theta;
      float xe0 = (src0 >= 0 && src0 < ODIM_) ? s_yatt[r][src0] : 0.f;
      float xe1 = (src1 >= 0 && src1 < ODIM_) ? s_yatt[r][src1] : 0.f;
      y0 -= ye0; y1 -= ye1;
      m_y[l] = y0; m_y[l + 64] = y1;
      m_xpad[127 + l]      -= xe0;
      m_xpad[127 + 64 + l] -= xe1;
    }
    __syncthreads();
  }
}

__global__ void k_finish(const WsHeader* __restrict__ h, float* __restrict__ out) {
  double s = (h->loss[0] + h->loss[1] + h->loss[2] + h->loss[3]) * 0.25;
  out[0] = (float)s;
}

extern "C" void kernel_launch(void* const* d_in, const int* in_sizes, int n_in,
                              void* d_out, int out_size, void* d_ws, size_t ws_size,
                              hipStream_t stream) {
  (void)in_sizes; (void)n_in; (void)out_size; (void)ws_size;
  const float* x     = (const float*)d_in[0];
  const float* y     = (const float*)d_in[1];
  const float* enc_w = (const float*)d_in[2];
  const float* enc_b = (const float*)d_in[3];
  const float* dec_w = (const float*)d_in[4];
  const float* dec_b = (const float*)d_in[5];
  float* out = (float*)d_out;
  WsHeader* hdr = (WsHeader*)d_ws;

  hipMemsetAsync(d_ws, 0, sizeof(WsHeader), stream);
  hipLaunchKernelGGL(k_count,  dim3(NROWS_ / 256), dim3(256), 0, stream, y, hdr);
  hipLaunchKernelGGL(k_main,   dim3(NROWS_ / RPB_), dim3(512), 0, stream,
                     x, y, enc_w, enc_b, dec_w, dec_b, hdr);
  hipLaunchKernelGGL(k_finish, dim3(1), dim3(1), 0, stream, hdr, out);
}

// Round 6
// 160.286 us; speedup vs baseline: 2.3141x; 1.0483x over previous
//
#include <hip/hip_runtime.h>
#include <math.h>

#define B_ 8
#define T_ 256
#define IDIM_ 128
#define ODIM_ 128
#define HDIM_ 512
#define CDIM_ 128
#define NROWS_ (B_*T_)
#define TEMPER_ 5.0f
#define ENERGY_TH_ 100.0f
#define N_ITER_ 4
#define XPAD_ 384   // [0,127) zeros | [127,255) x | [255,384) zeros
#define RPB_ 4      // rows per block, 2 waves each -> 512 threads

struct WsHeader {
  double loss[N_ITER_];
  unsigned int cnt_y_nz;
  unsigned int cnt_rows_nm;
};

// 8 blocks x 256 threads; one row per thread
__global__ __launch_bounds__(256) void k_count(const float* __restrict__ y,
                                               WsHeader* __restrict__ h) {
  __shared__ unsigned redn[256];
  __shared__ unsigned redr[256];
  const int tid = threadIdx.x;
  const int row = blockIdx.x * 256 + tid;
  const float4* yr = (const float4*)(y + row * ODIM_);
  unsigned c = 0;
  #pragma unroll 8
  for (int i = 0; i < 32; ++i) {
    float4 v = yr[i];
    c += (v.x != 0.f) + (v.y != 0.f) + (v.z != 0.f) + (v.w != 0.f);
  }
  redn[tid] = c;
  redr[tid] = (c > 0u) ? 1u : 0u;
  __syncthreads();
  for (int off = 128; off > 0; off >>= 1) {
    if (tid < off) { redn[tid] += redn[tid + off]; redr[tid] += redr[tid + off]; }
    __syncthreads();
  }
  if (tid == 0) {
    atomicAdd(&h->cnt_y_nz, redn[0]);
    atomicAdd(&h->cnt_rows_nm, redr[0]);
  }
}

__device__ inline float wsum(float p) {
  #pragma unroll
  for (int off = 32; off; off >>= 1) p += __shfl_xor(p, off, 64);
  return p;
}
__device__ inline float wmaxf(float p) {
  #pragma unroll
  for (int off = 32; off; off >>= 1) p = fmaxf(p, __shfl_xor(p, off, 64));
  return p;
}
__device__ inline void pick(float& v, int& i, float v2, int i2) {
  if (v2 > v || (v2 == v && i2 < i)) { v = v2; i = i2; }
}

// ---- radix-select: top-CDIM_ of 512 keys (8/lane, elem c = lane + 64k).
__device__ inline void radix_topk(const unsigned* key, unsigned* s_hist,
                                  int l, unsigned& t_out, int& rem_out) {
  unsigned prefix = 0u;
  int rem = CDIM_;
  #pragma unroll
  for (int shift = 24; shift >= 0; shift -= 8) {
    unsigned hi_mask = (shift == 24) ? 0u : (0xffffffffu << (shift + 8));
    #pragma unroll
    for (int i = 0; i < 4; ++i) s_hist[4 * l + i] = 0u;
    __threadfence_block();
    #pragma unroll
    for (int k = 0; k < 8; ++k) {
      if ((key[k] & hi_mask) == (prefix & hi_mask))
        atomicAdd(&s_hist[(key[k] >> shift) & 255u], 1u);
    }
    __threadfence_block();
    unsigned h0 = s_hist[4 * l], h1 = s_hist[4 * l + 1];
    unsigned h2 = s_hist[4 * l + 2], h3 = s_hist[4 * l + 3];
    unsigned sum4 = h0 + h1 + h2 + h3;
    unsigned s = sum4;
    #pragma unroll
    for (int off = 1; off < 64; off <<= 1) {
      unsigned o = __shfl(s, min(l + off, 63), 64);
      s += (l + off < 64) ? o : 0u;
    }
    unsigned exclHigh = s - sum4;
    unsigned suf3 = exclHigh;
    unsigned suf2 = suf3 + h3;
    unsigned suf1 = suf2 + h2;
    unsigned suf0 = suf1 + h1;
    unsigned r = (unsigned)rem;
    unsigned enc = 0xffffffffu;
    if (suf0 < r && suf0 + h0 >= r) enc = (suf0 << 8) | (unsigned)(4 * l + 0);
    if (suf1 < r && suf1 + h1 >= r) enc = (suf1 << 8) | (unsigned)(4 * l + 1);
    if (suf2 < r && suf2 + h2 >= r) enc = (suf2 << 8) | (unsigned)(4 * l + 2);
    if (suf3 < r && suf3 + h3 >= r) enc = (suf3 << 8) | (unsigned)(4 * l + 3);
    #pragma unroll
    for (int off = 32; off; off >>= 1) {
      unsigned o = (unsigned)__shfl_xor((int)enc, off, 64);
      enc = (o < enc) ? o : enc;
    }
    rem -= (int)(enc >> 8);
    prefix |= (enc & 255u) << shift;
  }
  t_out = prefix;
  rem_out = rem;
}

__global__ __launch_bounds__(512, 4) void k_main(
    const float* __restrict__ gx, const float* __restrict__ gy,
    const float* __restrict__ enc_w, const float* __restrict__ enc_b,
    const float* __restrict__ dec_w, const float* __restrict__ dec_b,
    WsHeader* __restrict__ hdr)
{
  const int tid = threadIdx.x;
  const int wid = tid >> 6;     // 0..7
  const int l   = tid & 63;
  const int r   = wid >> 1;     // row-in-block 0..3
  const int sub = wid & 1;      // wave within pair
  const int row = blockIdx.x * RPB_ + r;

  __shared__ __align__(16) float s_xpad[RPB_][XPAD_];
  __shared__ __align__(16) float s_y[RPB_][ODIM_];
  __shared__ __align__(16) float s_yatt[RPB_][ODIM_];
  __shared__ __align__(16) float s_h[RPB_][HDIM_];
  __shared__ __align__(16) float s_dot[RPB_][2][256];
  __shared__ __align__(16) float s_nx[RPB_][2][256];
  __shared__ float s_dpart[RPB_][2][ODIM_];
  __shared__ float s_scal[RPB_][2];
  __shared__ unsigned s_hist[RPB_][256];
  __shared__ unsigned long long s_pack[RPB_][CDIM_];

  float* m_xpad = s_xpad[r];
  float* m_y    = s_y[r];
  unsigned* m_hist = s_hist[r];
  unsigned long long* m_pack = s_pack[r];

  const unsigned long long lmask_lt = (l == 0) ? 0ull : ((1ull << l) - 1ull);
  const float* gxr = gx + row * IDIM_;
  const float* gyr = gy + row * ODIM_;

  // init: pair splits xpad; sub0 owns y registers + y LDS
  for (int t = l + 64 * sub; t < XPAD_; t += 128)
    m_xpad[t] = (t >= 127 && t < 127 + IDIM_) ? gxr[t - 127] : 0.f;

  float y0 = 0.f, y1 = 0.f;
  bool sq0 = false, sq1 = false, sm_row = false;
  if (sub == 0) {
    y0 = gyr[l]; y1 = gyr[l + 64];
    m_y[l] = y0; m_y[l + 64] = y1;
    sq0 = (y0 == 0.f); sq1 = (y1 == 0.f);
    sm_row = (__ballot((!sq0) || (!sq1)) == 0ull);
  }
  const float denom_ll = (float)max(hdr->cnt_y_nz, 1u);
  const float denomh   = (float)max(hdr->cnt_rows_nm * (unsigned)HDIM_, 1u);

  int mprev[8];
  #pragma unroll
  for (int k = 0; k < 8; ++k) mprev[k] = 0;

  int theta = 0;
  float row_lh = 0.f;

  __syncthreads();

  for (int iter = 0; iter < N_ITER_; ++iter) {
    // ========== P0: sim partials (each wave: half the j-range) ==========
    {
      const int jbase = 64 * sub;
      float yv = m_y[jbase + l];
      float pn = wsum(yv * yv);
      if (l == 0) s_scal[r][sub] = pn;

      float dot0 = 0, dot1 = 0, dot2 = 0, dot3 = 0;
      float nx0 = 0, nx1 = 0, nx2 = 0, nx3 = 0;
      const int m4 = 4 * l;
      float4 xq0 = *(const float4*)&m_xpad[m4 + jbase];
      #pragma unroll 4
      for (int jb = 0; jb < 16; ++jb) {
        float4 yq  = *(const float4*)&m_y[jbase + 4 * jb];
        float4 xq1 = *(const float4*)&m_xpad[m4 + jbase + 4 * jb + 4];
        float xa = xq0.x, xb = xq0.y, xc = xq0.z, xd = xq0.w;
        float xe_ = xq1.x, xf = xq1.y, xg = xq1.z;
        dot0 += xa * yq.x; nx0 += xa * xa; dot0 += xb * yq.y; nx0 += xb * xb;
        dot0 += xc * yq.z; nx0 += xc * xc; dot0 += xd * yq.w; nx0 += xd * xd;
        dot1 += xb * yq.x; nx1 += xb * xb; dot1 += xc * yq.y; nx1 += xc * xc;
        dot1 += xd * yq.z; nx1 += xd * xd; dot1 += xe_ * yq.w; nx1 += xe_ * xe_;
        dot2 += xc * yq.x; nx2 += xc * xc; dot2 += xd * yq.y; nx2 += xd * xd;
        dot2 += xe_ * yq.z; nx2 += xe_ * xe_; dot2 += xf * yq.w; nx2 += xf * xf;
        dot3 += xd * yq.x; nx3 += xd * xd; dot3 += xe_ * yq.y; nx3 += xe_ * xe_;
        dot3 += xf * yq.z; nx3 += xf * xf; dot3 += xg * yq.w; nx3 += xg * xg;
        xq0 = xq1;
      }
      float4 dq = {dot0, dot1, dot2, dot3};
      float4 nq = {nx0, nx1, nx2, nx3};
      *(float4*)&s_dot[r][sub][m4] = dq;
      *(float4*)&s_nx[r][sub][m4]  = nq;
    }
    __syncthreads();

    // ========== P1 (sub0): combine + argmax + softmax ==========
    if (sub == 0) {
      const float normy = sqrtf(s_scal[r][0] + s_scal[r][1]);
      float4 dA = *(const float4*)&s_dot[r][0][4 * l];
      float4 dB = *(const float4*)&s_dot[r][1][4 * l];
      float4 nA = *(const float4*)&s_nx[r][0][4 * l];
      float4 nB = *(const float4*)&s_nx[r][1][4 * l];
      float dot0 = dA.x + dB.x, dot1 = dA.y + dB.y;
      float dot2 = dA.z + dB.z, dot3 = dA.w + dB.w;
      float nx0 = nA.x + nB.x, nx1 = nA.y + nB.y;
      float nx2 = nA.z + nB.z, nx3 = nA.w + nB.w;
      float den, sv, bestv; int besti;
      den = normy * sqrtf(nx0); sv = (den == 0.f) ? 0.f : dot0 / den;
      bestv = sv; besti = 4 * l;
      den = normy * sqrtf(nx1); sv = (den == 0.f) ? 0.f : dot1 / den;
      pick(bestv, besti, sv, 4 * l + 1);
      den = normy * sqrtf(nx2); sv = (den == 0.f) ? 0.f : dot2 / den;
      pick(bestv, besti, sv, 4 * l + 2);
      if (4 * l + 3 < 255) {
        den = normy * sqrtf(nx3); sv = (den == 0.f) ? 0.f : dot3 / den;
        pick(bestv, besti, sv, 4 * l + 3);
      }
      #pragma unroll
      for (int off = 32; off; off >>= 1) {
        float ov = __shfl_xor(bestv, off, 64);
        int   oi = __shfl_xor(besti, off, 64);
        pick(bestv, besti, ov, oi);
      }
      theta = besti;

      float yal0 = m_xpad[theta + l];
      float yal1 = m_xpad[theta + l + 64];
      float z0 = yal0 * y0 / TEMPER_;
      float z1 = yal1 * y1 / TEMPER_;
      float zmax = wmaxf(fmaxf(z0, z1));
      float e0 = expf(z0 - zmax), e1 = expf(z1 - zmax);
      float esum = wsum(e0 + e1);
      s_yatt[r][l]      = yal0 * (e0 / esum);
      s_yatt[r][l + 64] = yal1 * (e1 / esum);
    }
    __syncthreads();

    // ========== P2 (all 512 threads): h[r'] = y_att[r'] @ enc_w + enc_b ====
    // 8-deep weight chunks: fits VGPR budget (no scratch spill), 8 loads in flight
    {
      const int c = tid;                    // one column per thread
      const float* wp = enc_w + c;
      float a0 = 0.f, a1 = 0.f, a2 = 0.f, a3 = 0.f;
      #pragma unroll 1
      for (int ch = 0; ch < 16; ++ch) {
        float w[8];
        #pragma unroll
        for (int k = 0; k < 8; ++k) w[k] = wp[(8 * ch + k) * HDIM_];
        #pragma unroll
        for (int q = 0; q < 2; ++q) {
          float4 ya0q = *(const float4*)&s_yatt[0][8 * ch + 4 * q];
          float4 ya1q = *(const float4*)&s_yatt[1][8 * ch + 4 * q];
          float4 ya2q = *(const float4*)&s_yatt[2][8 * ch + 4 * q];
          float4 ya3q = *(const float4*)&s_yatt[3][8 * ch + 4 * q];
          #pragma unroll
          for (int u = 0; u < 4; ++u) {
            float wv = w[4 * q + u];
            a0 += ((const float*)&ya0q)[u] * wv;
            a1 += ((const float*)&ya1q)[u] * wv;
            a2 += ((const float*)&ya2q)[u] * wv;
            a3 += ((const float*)&ya3q)[u] * wv;
          }
        }
      }
      float eb = enc_b[c];
      s_h[0][c] = a0 + eb;
      s_h[1][c] = a1 + eb;
      s_h[2][c] = a2 + eb;
      s_h[3][c] = a3 + eb;
    }
    __syncthreads();

    // ========== P3 (sub0): hsr radix + pack ==========
    if (sub == 0) {
      float hv[8]; unsigned key[8];
      #pragma unroll
      for (int k = 0; k < 8; ++k) {
        hv[k] = s_h[r][l + 64 * k];
        key[k] = __float_as_uint(hv[k] * hv[k]);
      }
      row_lh = 0.f;
      if (iter > 0) {
        unsigned t0; int rem0;
        radix_topk(key, m_hist, l, t0, rem0);
        int eqbefore = 0; float lacc = 0.f;
        #pragma unroll
        for (int k = 0; k < 8; ++k) {
          bool eq = (key[k] == t0);
          unsigned long long beq = __ballot(eq);
          int rank = eqbefore + __popcll(beq & lmask_lt);
          bool sel0 = (key[k] > t0) || (eq && rank < rem0);
          eqbefore += __popcll(beq);
          if (sel0 && mprev[k] > 0 && !sm_row) {
            float d = hv[k] - (1.f - (float)mprev[k]);
            lacc += (d * d) / denomh;
          }
        }
        row_lh = wsum(lacc);
        #pragma unroll
        for (int k = 0; k < 8; ++k) {
          if (mprev[k] > 0) hv[k] = 0.f;
          key[k] = __float_as_uint(hv[k] * hv[k]);
        }
      }
      unsigned t; int rem;
      radix_topk(key, m_hist, l, t, rem);
      int scount = 0, eqbefore = 0;
      #pragma unroll
      for (int k = 0; k < 8; ++k) {
        bool eq = (key[k] == t);
        unsigned long long beq = __ballot(eq);
        int rank = eqbefore + __popcll(beq & lmask_lt);
        bool sel = (key[k] > t) || (eq && rank < rem);
        eqbefore += __popcll(beq);
        unsigned long long mk = __ballot(sel);
        if (sel) {
          int pos = scount + __popcll(mk & lmask_lt);
          m_pack[pos] = (((unsigned long long)__float_as_uint(hv[k])) << 32)
                        | (unsigned)(l + 64 * k);
          mprev[k] += 1;
        }
        scount += (int)__popcll(mk);
      }
    }
    __syncthreads();

    // ========== P4: dec partials (each wave: 64 selected channels) ==========
    // 8-deep chunks (24 live regs) -- no scratch spill
    {
      float acc0 = 0.f, acc1 = 0.f;
      #pragma unroll 1
      for (int ch = 0; ch < 8; ++ch) {
        float hj[8], w0[8], w1[8];
        #pragma unroll
        for (int j = 0; j < 8; ++j) {
          unsigned long long pk = m_pack[64 * sub + 8 * ch + j];
          hj[j] = __uint_as_float((unsigned)(pk >> 32));
          const float* p = dec_w + (unsigned)(pk & 0xffffffffull) * (unsigned)ODIM_;
          w0[j] = p[l];
          w1[j] = p[l + 64];
        }
        #pragma unroll
        for (int j = 0; j < 8; ++j) {
          acc0 += hj[j] * w0[j];
          acc1 += hj[j] * w1[j];
        }
      }
      s_dpart[r][sub][l]      = acc0;
      s_dpart[r][sub][l + 64] = acc1;
    }
    __syncthreads();

    // ========== P5 (sub0): y_ele, loss, residuals ==========
    if (sub == 0) {
      float ye0 = (s_dpart[r][0][l]      + s_dpart[r][1][l])      + dec_b[l];
      float ye1 = (s_dpart[r][0][l + 64] + s_dpart[r][1][l + 64]) + dec_b[l + 64];

      float tshift  = fabsf((float)theta - 127.f);
      float menergy = tshift + 1.f;
      bool  mmask   = (tshift > ENERGY_TH_);
      float d0 = ye0 - y0, d1 = ye1 - y1;
      float ll0 = sq0 ? 0.f : d0 * d0; ll0 /= denom_ll; ll0 = mmask ? 0.f : ll0; ll0 /= menergy;
      float ll1 = sq1 ? 0.f : d1 * d1; ll1 /= denom_ll; ll1 = mmask ? 0.f : ll1; ll1 /= menergy;
      float row_ll = wsum(ll0 + ll1);
      if (l == 0) atomicAdd(&hdr->loss[iter], (double)(row_ll + row_lh));

      int src0 = l + 127 - theta;
      int src1 = l + 64 + 127 - theta;
      float xe0 = (src0 >= 0 && src0 < ODIM_) ? s_yatt[r][src0] : 0.f;
      float xe1 = (src1 >= 0 && src1 < ODIM_) ? s_yatt[r][src1] : 0.f;
      y0 -= ye0; y1 -= ye1;
      m_y[l] = y0; m_y[l + 64] = y1;
      m_xpad[127 + l]      -= xe0;
      m_xpad[127 + 64 + l] -= xe1;
    }
    __syncthreads();
  }
}

__global__ void k_finish(const WsHeader* __restrict__ h, float* __restrict__ out) {
  double s = (h->loss[0] + h->loss[1] + h->loss[2] + h->loss[3]) * 0.25;
  out[0] = (float)s;
}

extern "C" void kernel_launch(void* const* d_in, const int* in_sizes, int n_in,
                              void* d_out, int out_size, void* d_ws, size_t ws_size,
                              hipStream_t stream) {
  (void)in_sizes; (void)n_in; (void)out_size; (void)ws_size;
  const float* x     = (const float*)d_in[0];
  const float* y     = (const float*)d_in[1];
  const float* enc_w = (const float*)d_in[2];
  const float* enc_b = (const float*)d_in[3];
  const float* dec_w = (const float*)d_in[4];
  const float* dec_b = (const float*)d_in[5];
  float* out = (float*)d_out;
  WsHeader* hdr = (WsHeader*)d_ws;

  hipMemsetAsync(d_ws, 0, sizeof(WsHeader), stream);
  hipLaunchKernelGGL(k_count,  dim3(NROWS_ / 256), dim3(256), 0, stream, y, hdr);
  hipLaunchKernelGGL(k_main,   dim3(NROWS_ / RPB_), dim3(512), 0, stream,
                     x, y, enc_w, enc_b, dec_w, dec_b, hdr);
  hipLaunchKernelGGL(k_finish, dim3(1), dim3(1), 0, stream, hdr, out);
}